// Round 5
// baseline (2408.869 us; speedup 1.0000x reference)
//
#include <hip/hip_runtime.h>
#include <stdint.h>
#include <math.h>

#define B_SZ 1024
#define NV   4096
#define NH   4096
#define NSGN 2048

typedef short bf16x8 __attribute__((ext_vector_type(8)));
typedef short bf16x4 __attribute__((ext_vector_type(4)));
typedef float f32x4  __attribute__((ext_vector_type(4)));

// ---------------- threefry2x32 (JAX-compatible, 20 rounds) ----------------
__host__ __device__ __forceinline__ void tf2x32(uint32_t k0, uint32_t k1,
                                                uint32_t x0, uint32_t x1,
                                                uint32_t& o0, uint32_t& o1)
{
    uint32_t k2 = k0 ^ k1 ^ 0x1BD11BDAu;
#define TFR(r) { x0 += x1; x1 = (x1 << (r)) | (x1 >> (32 - (r))); x1 ^= x0; }
    x0 += k0; x1 += k1;
    TFR(13) TFR(15) TFR(26) TFR(6)
    x0 += k1; x1 += k2 + 1u;
    TFR(17) TFR(29) TFR(16) TFR(24)
    x0 += k2; x1 += k0 + 2u;
    TFR(13) TFR(15) TFR(26) TFR(6)
    x0 += k0; x1 += k1 + 3u;
    TFR(17) TFR(29) TFR(16) TFR(24)
    x0 += k1; x1 += k2 + 4u;
    TFR(13) TFR(15) TFR(26) TFR(6)
    x0 += k2; x1 += k0 + 5u;
#undef TFR
    o0 = x0; o1 = x1;
}

__device__ __forceinline__ float tf_uniform01(uint32_t k0, uint32_t k1, uint32_t idx)
{
    uint32_t a, b;
    tf2x32(k0, k1, 0u, idx, a, b);
    uint32_t bits = a ^ b;
    uint32_t fb = (bits >> 9) | 0x3F800000u;
    return __uint_as_float(fb) - 1.0f;
}

__device__ __forceinline__ float sigmoidf_(float x)
{
    if (x >= 0.0f) { float e = expf(-x); return 1.0f / (1.0f + e); }
    float e = expf(x); return e / (1.0f + e);
}

__device__ __forceinline__ short f2bf_trunc(float f)
{
    return (short)(__float_as_uint(f) >> 16);
}
__device__ __forceinline__ float bf2f(short s)
{
    return __uint_as_float(((uint32_t)(uint16_t)s) << 16);
}

__device__ __forceinline__ void gl16(const void* g, void* l)
{
    __builtin_amdgcn_global_load_lds((const __attribute__((address_space(1))) void*)g,
                                     (__attribute__((address_space(3))) void*)l, 16, 0, 0);
}

// ---------------- weight precompute: fp32 -> hi/lo bf16 (trunc split) ----------------
__global__ __launch_bounds__(256) void conv_bt(const float* __restrict__ W,
                                               short* __restrict__ Wh, short* __restrict__ Wl)
{
    size_t i = ((size_t)blockIdx.x * 256 + threadIdx.x) * 4;
    f32x4 v = *(const f32x4*)(W + i);
    short h[4], l[4];
#pragma unroll
    for (int c = 0; c < 4; ++c) {
        uint32_t u = __float_as_uint(v[c]);
        h[c] = (short)(u >> 16);
        float hf = __uint_as_float(u & 0xFFFF0000u);
        l[c] = f2bf_trunc(v[c] - hf);
    }
    *(bf16x4*)(Wh + i) = *(bf16x4*)h;
    *(bf16x4*)(Wl + i) = *(bf16x4*)l;
}

// =====================================================================
// Fused GEMM + sampling epilogue, depth-1 double-buffered pipeline (T3).
// LDS subtiles (16 rows x 32 k) in MFMA-fragment order (slot L = row L&15,
// kchunk L>>4). bt staging = global_load_lds (fragment-order source);
// bn staging = reg loads issued EARLY, ds_write (subtile-XOR swizzle) LATE.
//  MODE 0: K=4096 bt.  MODE 1: K=8192 concat (bt then bn).  MODE 2: K=4096 bn.
//  EPI 0: bern -> O0.  EPI 1: dual write.  EPI 2: sign sampling (vneg).
// tile 64(M) x 128(N), 256 threads = 4 waves, grid (32,16)
// =====================================================================
template<int EPI, int MODE>
__global__ __launch_bounds__(256) void mm_fast(
    const short* __restrict__ A0, const short* __restrict__ A1,
    const short* __restrict__ BH0, const short* __restrict__ BL0,
    const short* __restrict__ BH1, const short* __restrict__ BL1,
    const float* __restrict__ bias, const float* __restrict__ occ,
    short* __restrict__ O0, short* __restrict__ O1,
    uint32_t rk0, uint32_t rk1)
{
    __shared__ __align__(1024) short As[2][4 * 512];
    __shared__ __align__(1024) short Bhs[2][8 * 512];
    __shared__ __align__(1024) short Bls[2][8 * 512];

    const int tid = threadIdx.x;
    const int bn = blockIdx.x * 128, bm = blockIdx.y * 64;
    const int wv = tid >> 6, lane = tid & 63;
    const int wr = (wv >> 1) * 32, wc = (wv & 1) * 64;
    const int l15 = lane & 15, l4 = lane >> 4;

    // bt staging: fragment-order per-lane source
    const int fr = lane & 15;
    const int fc = (lane >> 4) * 8;

    // bn staging: thread -> 4 cols x 4 k
    const int cg = (tid & 31) * 4;
    const int kg = tid >> 5;
    const int qsub = (tid & 31) >> 2;
    const int koff = (kg >> 1) * 128 + (kg & 1) * 4;

    f32x4 acc[2][4] = {};
    short th[4][4], tl[4][4];

    const int NSTEPS = (MODE == 1) ? 256 : 128;
    // step t is bt iff MODE0, or MODE1 && t < 128
    auto is_bt = [&](int t) -> bool {
        return (MODE == 0) || (MODE == 1 && t < 128);
    };

    auto stage_bt = [&](int buf, int kk) {
#pragma unroll
        for (int c = 0; c < 5; ++c) {
            int u = wv * 5 + c;
            if (u < 4) {
                gl16(A0 + (size_t)(bm + u * 16 + fr) * 4096 + kk + fc, &As[buf][u * 512]);
            } else if (u < 12) {
                int s = u - 4;
                gl16(BH0 + (size_t)(bn + s * 16 + fr) * 4096 + kk + fc, &Bhs[buf][s * 512]);
            } else {
                int s = u - 12;
                gl16(BL0 + (size_t)(bn + s * 16 + fr) * 4096 + kk + fc, &Bls[buf][s * 512]);
            }
        }
    };
    auto stage_bn_load = [&](int buf, int kk) {
        const short* A  = (MODE == 1) ? A1 : A0;
        const short* BH = (MODE == 1) ? BH1 : BH0;
        const short* BL = (MODE == 1) ? BL1 : BL0;
        // B reg loads first (so their waitcnt doesn't force draining A's gl16)
#pragma unroll
        for (int i = 0; i < 4; ++i) {
            *(bf16x4*)th[i] = *(const bf16x4*)(BH + (size_t)(kk + kg * 4 + i) * 4096 + bn + cg);
            *(bf16x4*)tl[i] = *(const bf16x4*)(BL + (size_t)(kk + kg * 4 + i) * 4096 + bn + cg);
        }
        gl16(A + (size_t)(bm + wv * 16 + fr) * 4096 + kk + fc, &As[buf][wv * 512]);
    };
    auto stage_bn_write = [&](int buf) {
#pragma unroll
        for (int j = 0; j < 4; ++j) {
            int r = (tid & 3) * 4 + j;
            int off = qsub * 512 + koff + ((r ^ qsub) & 15) * 8;
            short wh[4] = {th[0][j], th[1][j], th[2][j], th[3][j]};
            short wl[4] = {tl[0][j], tl[1][j], tl[2][j], tl[3][j]};
            *(bf16x4*)&Bhs[buf][off] = *(bf16x4*)wh;
            *(bf16x4*)&Bls[buf][off] = *(bf16x4*)wl;
        }
    };

    // prologue: stage step 0 into buffer 0
    if (is_bt(0)) {
        stage_bt(0, 0);
    } else {
        stage_bn_load(0, 0);
        stage_bn_write(0);
    }
    __syncthreads();

    for (int t = 0; t < NSTEPS; ++t) {
        const int cur = t & 1, nxt = cur ^ 1;
        const bool cbt = is_bt(t);
        const bool hn = (t + 1 < NSTEPS);
        const bool nbt = hn && is_bt(t + 1);

        // 1) issue next step's global ops into the other buffer
        if (hn) {
            int kk1 = ((t + 1) * 32) & 4095;
            if (nbt) stage_bt(nxt, kk1);
            else     stage_bn_load(nxt, kk1);
        }

        // 2) compute current buffer
        bf16x8 af[2], bhf[4], blf[4];
#pragma unroll
        for (int m = 0; m < 2; ++m)
            af[m] = *(bf16x8*)&As[cur][((wv >> 1) * 2 + m) * 512 + lane * 8];
#pragma unroll
        for (int n = 0; n < 4; ++n) {
            int sn = (wv & 1) * 4 + n;
            int boff = cbt ? sn * 512 + lane * 8
                           : sn * 512 + l4 * 128 + ((l15 ^ sn) & 15) * 8;
            bhf[n] = *(bf16x8*)&Bhs[cur][boff];
            blf[n] = *(bf16x8*)&Bls[cur][boff];
        }
#pragma unroll
        for (int m = 0; m < 2; ++m)
#pragma unroll
            for (int n = 0; n < 4; ++n) {
                acc[m][n] = __builtin_amdgcn_mfma_f32_16x16x32_bf16(af[m], bhf[n], acc[m][n], 0, 0, 0);
                acc[m][n] = __builtin_amdgcn_mfma_f32_16x16x32_bf16(af[m], blf[n], acc[m][n], 0, 0, 0);
            }

        // 3) finish next step's bn staging (ds_write after compute)
        if (hn && !nbt) stage_bn_write(nxt);

        __syncthreads();
    }

    // ---- fused sampling epilogue ----
#pragma unroll
    for (int m = 0; m < 2; ++m)
#pragma unroll
        for (int n = 0; n < 4; ++n)
#pragma unroll
            for (int r = 0; r < 4; ++r) {
                int row = bm + wr + m * 16 + l4 * 4 + r;
                int col = bn + wc + n * 16 + l15;
                float val = acc[m][n][r];
                if (EPI == 2) {
                    if (col & 1) {
                        int s = (col - 1) >> 1;
                        uint32_t e = (uint32_t)(row * 2048 + s);
                        float p = sigmoidf_(val + bias[col]);
                        float u = tf_uniform01(rk0, rk1, e);
                        O0[(size_t)row * 4096 + col] = (u < p) ? (short)0x3F80 : (short)0;
                    } else {
                        O0[(size_t)row * 4096 + col] =
                            (occ[(size_t)row * 2048 + (col >> 1)] != 0.0f) ? (short)0x3F80 : (short)0;
                    }
                } else {
                    size_t e = (size_t)row * 4096 + col;
                    float p = sigmoidf_(val + bias[col]);
                    float u = tf_uniform01(rk0, rk1, (uint32_t)e);
                    short sv = (u < p) ? (short)0x3F80 : (short)0;
                    O0[e] = sv;
                    if (EPI == 1) O1[e] = sv;
                }
            }
}

// =====================================================================
// Gradient GEMM (exact): Out[i,j] = (sum_b Xn Yn - Xp Yp)/1024
// K-concat 64 steps of 32 b (neg 32, pos 32; pos-Y sign-negated).
// Fragment-order subtiles with (r ^ subtile) swizzle; reg prefetch (T14).
// tile 128x128, 256 threads = 4 waves (64x64 each)
// =====================================================================
template<int W1MODE>
__global__ __launch_bounds__(256) void grad_mm(
    const short* __restrict__ Xn, const short* __restrict__ Yn,
    const short* __restrict__ Xp, const short* __restrict__ Yp_bf,
    const float* __restrict__ Yp_f32,
    float* __restrict__ Out)
{
    __shared__ __align__(1024) short Xs[2][8 * 512];
    __shared__ __align__(1024) short Ys[2][8 * 512];

    const int tid = threadIdx.x;
    const int bi = blockIdx.y * 128, bj = blockIdx.x * 128;
    const int wv = tid >> 6, lane = tid & 63;
    const int wr = (wv >> 1) * 64, wc = (wv & 1) * 64;
    const int l15 = lane & 15, l4 = lane >> 4;

    const int cg = (tid & 31) * 4;
    const int kg = tid >> 5;
    const int qsub = (tid & 31) >> 2;
    const int koff = (kg >> 1) * 128 + (kg & 1) * 4;

    f32x4 acc[4][4] = {};
    short xr[4][4];
    short yr[4][4];

    auto loadT = [&](int bt) {
        const bool neg = bt < 32;
        const int b0 = (bt & 31) * 32;
        const short* X = neg ? Xn : Xp;
#pragma unroll
        for (int i = 0; i < 4; ++i)
            *(bf16x4*)xr[i] = *(const bf16x4*)(X + (size_t)(b0 + kg * 4 + i) * NH + bi + cg);
        if (W1MODE) {
            if (neg) {
#pragma unroll
                for (int i = 0; i < 4; ++i) {
                    bf16x8 v = *(const bf16x8*)(Yn + (size_t)(b0 + kg * 4 + i) * NV + 2 * (bj + cg));
                    yr[i][0] = v[1]; yr[i][1] = v[3]; yr[i][2] = v[5]; yr[i][3] = v[7];
                }
            } else {
#pragma unroll
                for (int i = 0; i < 4; ++i) {
                    const float* p = Yp_f32 + (size_t)(b0 + kg * 4 + i) * NV + 2 * (bj + cg);
                    f32x4 a = *(const f32x4*)p;
                    f32x4 b = *(const f32x4*)(p + 4);
                    yr[i][0] = f2bf_trunc(-a[1]); yr[i][1] = f2bf_trunc(-a[3]);
                    yr[i][2] = f2bf_trunc(-b[1]); yr[i][3] = f2bf_trunc(-b[3]);
                }
            }
        } else {
            const short* Y = neg ? Yn : Yp_bf;
            const short sx = neg ? (short)0 : (short)0x8000;
#pragma unroll
            for (int i = 0; i < 4; ++i) {
                bf16x4 v = *(const bf16x4*)(Y + (size_t)(b0 + kg * 4 + i) * NH + bj + cg);
#pragma unroll
                for (int j = 0; j < 4; ++j) yr[i][j] = (short)(v[j] ^ sx);
            }
        }
    };
    auto writeT = [&](int buf) {
#pragma unroll
        for (int j = 0; j < 4; ++j) {
            int r = (tid & 3) * 4 + j;
            int off = qsub * 512 + koff + ((r ^ qsub) & 15) * 8;
            short wx[4] = {xr[0][j], xr[1][j], xr[2][j], xr[3][j]};
            short wy[4] = {yr[0][j], yr[1][j], yr[2][j], yr[3][j]};
            *(bf16x4*)&Xs[buf][off] = *(bf16x4*)wx;
            *(bf16x4*)&Ys[buf][off] = *(bf16x4*)wy;
        }
    };

    loadT(0);
    writeT(0);
    __syncthreads();

    for (int bt = 0; bt < 64; ++bt) {
        const int cur = bt & 1;
        if (bt + 1 < 64) loadT(bt + 1);

        bf16x8 xf[4], yf[4];
#pragma unroll
        for (int m = 0; m < 4; ++m) {
            int sm = (wv >> 1) * 4 + m;
            xf[m] = *(bf16x8*)&Xs[cur][sm * 512 + l4 * 128 + ((l15 ^ sm) & 15) * 8];
        }
#pragma unroll
        for (int n = 0; n < 4; ++n) {
            int sn = (wv & 1) * 4 + n;
            yf[n] = *(bf16x8*)&Ys[cur][sn * 512 + l4 * 128 + ((l15 ^ sn) & 15) * 8];
        }
#pragma unroll
        for (int m = 0; m < 4; ++m)
#pragma unroll
            for (int n = 0; n < 4; ++n)
                acc[m][n] = __builtin_amdgcn_mfma_f32_16x16x32_bf16(xf[m], yf[n], acc[m][n], 0, 0, 0);

        if (bt + 1 < 64) writeT(cur ^ 1);
        __syncthreads();
    }

    const float invB = 1.0f / 1024.0f;
#pragma unroll
    for (int m = 0; m < 4; ++m)
#pragma unroll
        for (int n = 0; n < 4; ++n)
#pragma unroll
            for (int r = 0; r < 4; ++r) {
                int i_ = bi + wr + m * 16 + l4 * 4 + r;
                int j_ = bj + wc + n * 16 + l15;
                if (W1MODE) {
                    Out[(size_t)i_ * NV + 2 * j_ + 1] = acc[m][n][r] * invB;
                    Out[(size_t)i_ * NV + 2 * j_]     = 0.0f;
                } else {
                    Out[(size_t)i_ * NH + j_] = acc[m][n][r] * invB;
                }
            }
}

// ---------------- small kernels ----------------
__global__ void cvt_kernel(const float* __restrict__ in, short* __restrict__ out, int n)
{
    int e = blockIdx.x * 256 + threadIdx.x;
    if (e < n) out[e] = (in[e] != 0.0f) ? (short)0x3F80 : (short)0;
}

__global__ void dbv_fast(const float* __restrict__ vdata, const short* __restrict__ vneg,
                         float* __restrict__ out)
{
    __shared__ float part[4][64];
    int c = threadIdx.x & 63, rg = threadIdx.x >> 6;
    int s = blockIdx.x * 64 + c;
    float acc = 0.0f;
    for (int b = rg; b < B_SZ; b += 4)
        acc += bf2f(vneg[(size_t)b * NV + 2 * s + 1]) - vdata[(size_t)b * NV + 2 * s + 1];
    part[rg][c] = acc;
    __syncthreads();
    if (rg == 0) {
        out[2 * s + 1] = (part[0][c] + part[1][c] + part[2][c] + part[3][c]) * (1.0f / 1024.0f);
        out[2 * s] = 0.0f;
    }
}

__global__ void dbh_fast(const short* __restrict__ Xp, const short* __restrict__ Xn,
                         float* __restrict__ out)
{
    __shared__ int part[4][64];
    int c = threadIdx.x & 63, rg = threadIdx.x >> 6;
    int j = blockIdx.x * 64 + c;
    int acc = 0;
    for (int b = rg; b < B_SZ; b += 4)
        acc += (int)(Xn[(size_t)b * NH + j] != 0) - (int)(Xp[(size_t)b * NH + j] != 0);
    part[rg][c] = acc;
    __syncthreads();
    if (rg == 0)
        out[j] = (float)(part[0][c] + part[1][c] + part[2][c] + part[3][c]) * (1.0f / 1024.0f);
}

__global__ void zero_kernel(unsigned* p) { *p = 0u; }

__global__ void loss_count2(const float* __restrict__ vdata,
                            const short* __restrict__ vneg, unsigned* cnt)
{
    __shared__ int part[4];
    int t = blockIdx.x * 256 + threadIdx.x;
    int local = 0;
#pragma unroll
    for (int it = 0; it < 8; ++it) {
        int e = t + it * 262144;
        int b = e >> 11, s = e & 2047;
        float st = vdata[(size_t)b * NV + 2 * s + 1];
        float sp = bf2f(vneg[(size_t)b * NV + 2 * s + 1]);
        local += (st != sp) ? 1 : 0;
    }
#pragma unroll
    for (int off = 32; off; off >>= 1) local += __shfl_down(local, off, 64);
    if ((threadIdx.x & 63) == 0) part[threadIdx.x >> 6] = local;
    __syncthreads();
    if (threadIdx.x == 0)
        atomicAdd(cnt, (unsigned)(part[0] + part[1] + part[2] + part[3]));
}

__global__ void loss_final_kernel(const unsigned* cnt, float* out, float lp, float lm)
{
    float mis = (float)(*cnt);
    float mat = 2097152.0f - mis;
    out[0] = -((mat * lp + mis * lm) * (1.0f / 2097152.0f));
}

// ---------------- host ----------------
extern "C" void kernel_launch(void* const* d_in, const int* in_sizes, int n_in,
                              void* d_out, int out_size, void* d_ws, size_t ws_size,
                              hipStream_t stream)
{
    (void)in_sizes; (void)n_in; (void)out_size; (void)ws_size;
    const float* v_data = (const float*)d_in[0];
    const float* occ    = (const float*)d_in[1];
    const float* W1     = (const float*)d_in[2];
    const float* b_v    = (const float*)d_in[3];
    const float* b_h1   = (const float*)d_in[4];
    const float* W2     = (const float*)d_in[5];
    const float* b_h2   = (const float*)d_in[6];
    float* out = (float*)d_out;

    char* w = (char*)d_ws;
    short* vneg = (short*)w;
    short* h1d  = vneg + (size_t)B_SZ * NV;
    short* h2d  = h1d  + (size_t)B_SZ * NH;
    short* h1c  = h2d  + (size_t)B_SZ * NH;
    short* h2n  = h1c  + (size_t)B_SZ * NH;
    unsigned* cnt = (unsigned*)(h2n + (size_t)B_SZ * NH);

    // d_out doubles as weight scratch during the forward phase.
    short* W1h = (short*)(((uintptr_t)(out + 1) + 15) & ~(uintptr_t)15);
    short* W1l = W1h + (size_t)NH * NV;
    short* W2h = W1l + (size_t)NH * NV;
    short* W2l = W2h + (size_t)NH * NH;

    // ---- JAX key derivation ----
    const uint32_t r0 = 0u, r1 = 42u;
    uint32_t kp1a, kp1b, kp2a, kp2b, kfa, kfb, kla, klb;
    tf2x32(r0, r1, 0u, 0u, kp1a, kp1b);
    tf2x32(r0, r1, 0u, 1u, kp2a, kp2b);
    tf2x32(r0, r1, 0u, 2u, kfa, kfb);
    tf2x32(r0, r1, 0u, 3u, kla, klb);
    uint32_t kaA[2], kaB[2], kbA[2], kbB[2], kcA[2], kcB[2];
    for (int i = 0; i < 2; ++i) {
        uint32_t fa, fb;
        tf2x32(kla, klb, 0u, (uint32_t)i, fa, fb);
        tf2x32(fa, fb, 0u, 0u, kaA[i], kaB[i]);
        tf2x32(fa, fb, 0u, 1u, kbA[i], kbB[i]);
        tf2x32(fa, fb, 0u, 2u, kcA[i], kcB[i]);
    }

    const int T = 256;
    const int NELEM = B_SZ * NH;
    dim3 gMM(NV / 128, B_SZ / 64);     // 32 x 16 = 512 blocks

    conv_bt<<<(NH * NV) / (4 * 256), 256, 0, stream>>>(W1, W1h, W1l);
    conv_bt<<<(NH * NH) / (4 * 256), 256, 0, stream>>>(W2, W2h, W2l);

    cvt_kernel<<<NELEM / T, T, 0, stream>>>(v_data, vneg, NELEM);

    // positive phase
    mm_fast<0, 0><<<gMM, 256, 0, stream>>>(vneg, nullptr, W1h, W1l, nullptr, nullptr,
                                           b_h1, nullptr, h1d, nullptr, kp1a, kp1b);
    mm_fast<1, 0><<<gMM, 256, 0, stream>>>(h1d, nullptr, W2h, W2l, nullptr, nullptr,
                                           b_h2, nullptr, h2d, h2n, kp2a, kp2b);

    // Gibbs loop (k = 2)
    for (int i = 0; i < 2; ++i) {
        mm_fast<0, 1><<<gMM, 256, 0, stream>>>(vneg, h2n, W1h, W1l, W2h, W2l,
                                               b_h1, nullptr, h1c, nullptr, kaA[i], kaB[i]);
        mm_fast<0, 0><<<gMM, 256, 0, stream>>>(h1c, nullptr, W2h, W2l, nullptr, nullptr,
                                               b_h2, nullptr, h2n, nullptr, kbA[i], kbB[i]);
        mm_fast<2, 2><<<gMM, 256, 0, stream>>>(h1c, nullptr, W1h, W1l, nullptr, nullptr,
                                               b_v, occ, vneg, nullptr, kcA[i], kcB[i]);
    }

    // final hidden refresh
    mm_fast<0, 1><<<gMM, 256, 0, stream>>>(vneg, h2n, W1h, W1l, W2h, W2l,
                                           b_h1, nullptr, h1c, nullptr, kfa, kfb);

    // outputs (weight scratch dead after this point)
    float* dW1o  = out + 1;
    float* dbvo  = dW1o + (size_t)NH * NV;
    float* dbh1o = dbvo + NV;
    float* dW2o  = dbh1o + NH;
    float* dbh2o = dW2o + (size_t)NH * NH;

    grad_mm<1><<<dim3(NSGN / 128, NH / 128), T, 0, stream>>>(h1c, vneg, h1d, (short*)nullptr, v_data, dW1o);
    grad_mm<0><<<dim3(NH / 128, NH / 128), T, 0, stream>>>(h1c, h2n, h1d, h2d, (const float*)nullptr, dW2o);
    dbv_fast<<<NSGN / 64, T, 0, stream>>>(v_data, vneg, dbvo);
    dbh_fast<<<NH / 64, T, 0, stream>>>(h1d, h1c, dbh1o);
    dbh_fast<<<NH / 64, T, 0, stream>>>(h2d, h2n, dbh2o);

    zero_kernel<<<1, 1, 0, stream>>>(cnt);
    loss_count2<<<1024, T, 0, stream>>>(v_data, vneg, cnt);
    loss_final_kernel<<<1, 1, 0, stream>>>(cnt, out, logf(1.0f + 1e-7f), logf(1e-7f));
}

// Round 6
// 1977.032 us; speedup vs baseline: 1.2184x; 1.2184x over previous
//
#include <hip/hip_runtime.h>
#include <stdint.h>
#include <math.h>

#define B_SZ 1024
#define NV   4096
#define NH   4096
#define NSGN 2048

typedef short bf16x8 __attribute__((ext_vector_type(8)));
typedef short bf16x4 __attribute__((ext_vector_type(4)));
typedef float f32x4  __attribute__((ext_vector_type(4)));
typedef _Float16 f16x8 __attribute__((ext_vector_type(8)));

#define F16_ONE  ((short)0x3C00)
#define F16_NEG1 ((short)0xBC00)

// ---------------- threefry2x32 (JAX-compatible, 20 rounds) ----------------
__host__ __device__ __forceinline__ void tf2x32(uint32_t k0, uint32_t k1,
                                                uint32_t x0, uint32_t x1,
                                                uint32_t& o0, uint32_t& o1)
{
    uint32_t k2 = k0 ^ k1 ^ 0x1BD11BDAu;
#define TFR(r) { x0 += x1; x1 = (x1 << (r)) | (x1 >> (32 - (r))); x1 ^= x0; }
    x0 += k0; x1 += k1;
    TFR(13) TFR(15) TFR(26) TFR(6)
    x0 += k1; x1 += k2 + 1u;
    TFR(17) TFR(29) TFR(16) TFR(24)
    x0 += k2; x1 += k0 + 2u;
    TFR(13) TFR(15) TFR(26) TFR(6)
    x0 += k0; x1 += k1 + 3u;
    TFR(17) TFR(29) TFR(16) TFR(24)
    x0 += k1; x1 += k2 + 4u;
    TFR(13) TFR(15) TFR(26) TFR(6)
    x0 += k2; x1 += k0 + 5u;
#undef TFR
    o0 = x0; o1 = x1;
}

__device__ __forceinline__ float tf_uniform01(uint32_t k0, uint32_t k1, uint32_t idx)
{
    uint32_t a, b;
    tf2x32(k0, k1, 0u, idx, a, b);
    uint32_t bits = a ^ b;
    uint32_t fb = (bits >> 9) | 0x3F800000u;
    return __uint_as_float(fb) - 1.0f;
}

__device__ __forceinline__ float sigmoidf_(float x)
{
    if (x >= 0.0f) { float e = expf(-x); return 1.0f / (1.0f + e); }
    float e = expf(x); return e / (1.0f + e);
}

__device__ __forceinline__ void gl16(const void* g, void* l)
{
    __builtin_amdgcn_global_load_lds((const __attribute__((address_space(1))) void*)g,
                                     (__attribute__((address_space(3))) void*)l, 16, 0, 0);
}

// ---------------- weight precompute: fp32 -> fp16 (RNE) ----------------
__global__ __launch_bounds__(256) void conv_f16(const float* __restrict__ W,
                                                short* __restrict__ Wf)
{
    size_t i = ((size_t)blockIdx.x * 256 + threadIdx.x) * 4;
    f32x4 v = *(const f32x4*)(W + i);
    short h[4];
#pragma unroll
    for (int c = 0; c < 4; ++c) {
        union { _Float16 f; short s; } u;
        u.f = (_Float16)v[c];
        h[c] = u.s;
    }
    *(bf16x4*)(Wf + i) = *(bf16x4*)h;
}

// =====================================================================
// Fused fp16 GEMM + sampling epilogue, 128x128 tile, 512 thr (8 waves),
// depth-1 LDS double buffer. Subtiles (16 rows x 32 k = 512 shorts) in
// MFMA-fragment order (slot L = row L&15, kchunk L>>4).
//  bt staging: global_load_lds, fragment-order per-lane source.
//  bn staging: reg loads early, XOR-swizzled ds_write late.
//  MODE 0: K=4096 bt.  MODE 1: K=8192 concat (bt then bn).  MODE 2: K=4096 bn.
//  EPI 0: bern -> O0.  EPI 1: dual write.  EPI 2: sign sampling (vneg).
// Grid 256 (1-D), XCD-swizzled: XCD x owns bn-panels {4x..4x+3} x all bm
// (per-XCD B working set = 4 MB = one L2).
// =====================================================================
template<int EPI, int MODE>
__global__ __launch_bounds__(512) void mm_fast(
    const short* __restrict__ A0, const short* __restrict__ A1,
    const short* __restrict__ B0, const short* __restrict__ B1,
    const float* __restrict__ bias, const float* __restrict__ occ,
    short* __restrict__ O0, short* __restrict__ O1,
    uint32_t rk0, uint32_t rk1)
{
    __shared__ __align__(1024) short As[2][8 * 512];
    __shared__ __align__(1024) short Bs[2][8 * 512];

    const int bid = blockIdx.x;
    const int xcd = bid & 7, slot = bid >> 3;
    const int bn = (xcd * 4 + (slot & 3)) * 128;
    const int bm = (slot >> 2) * 128;

    const int tid = threadIdx.x;
    const int wv = tid >> 6, lane = tid & 63;
    const int l15 = lane & 15, l4 = lane >> 4;
    const int fr = l15, fc = l4 * 8;      // fragment-order source coords
    const int cg = (tid & 63) * 2;        // bn staging: col base

    f32x4 acc[2][4] = {};
    short tb[4][2];                       // bn staging regs: [k-sub][col-sub]

    const int NSTEPS = (MODE == 1) ? 256 : 128;
    auto is_bt = [&](int t) { return (MODE == 0) || (MODE == 1 && t < 128); };

    auto stage_bt = [&](int buf, int kk) {
        gl16(A0 + (size_t)(bm + wv * 16 + fr) * 4096 + kk + fc, &As[buf][wv * 512]);
        gl16(B0 + (size_t)(bn + wv * 16 + fr) * 4096 + kk + fc, &Bs[buf][wv * 512]);
    };
    auto stage_bn_load = [&](int buf, int kk) {
        const short* A = (MODE == 1) ? A1 : A0;
        const short* B = (MODE == 1) ? B1 : B0;
#pragma unroll
        for (int i = 0; i < 4; ++i)
            *(uint32_t*)&tb[i][0] = *(const uint32_t*)(B + (size_t)(kk + wv * 4 + i) * 4096 + bn + cg);
        gl16(A + (size_t)(bm + wv * 16 + fr) * 4096 + kk + fc, &As[buf][wv * 512]);
    };
    auto stage_bn_write = [&](int buf) {
#pragma unroll
        for (int j = 0; j < 2; ++j) {
            int col = cg + j;
            int sn = col >> 4;
            int L = ((col & 15) ^ sn) + ((wv >> 1) << 4);
            short w4[4] = { tb[0][j], tb[1][j], tb[2][j], tb[3][j] };
            *(bf16x4*)&Bs[buf][sn * 512 + L * 8 + (wv & 1) * 4] = *(bf16x4*)w4;
        }
    };

    // prologue
    if (is_bt(0)) {
        stage_bt(0, 0);
    } else {
        stage_bn_load(0, 0);
        stage_bn_write(0);
    }
    __syncthreads();

    for (int t = 0; t < NSTEPS; ++t) {
        const int cur = t & 1, nxt = cur ^ 1;
        const bool cbt = is_bt(t);
        const bool hn = (t + 1 < NSTEPS);
        const bool nbt = hn && is_bt(t + 1);

        if (hn) {
            int kk1 = ((t + 1) * 32) & 4095;
            if (nbt) stage_bt(nxt, kk1);
            else     stage_bn_load(nxt, kk1);
        }

        f16x8 af[2], bf[4];
#pragma unroll
        for (int m = 0; m < 2; ++m)
            af[m] = *(f16x8*)&As[cur][((wv >> 1) * 2 + m) * 512 + lane * 8];
#pragma unroll
        for (int n = 0; n < 4; ++n) {
            int sn = (wv & 1) * 4 + n;
            int off = cbt ? sn * 512 + lane * 8
                          : sn * 512 + l4 * 128 + ((l15 ^ sn) & 15) * 8;
            bf[n] = *(f16x8*)&Bs[cur][off];
        }
#pragma unroll
        for (int m = 0; m < 2; ++m)
#pragma unroll
            for (int n = 0; n < 4; ++n)
                acc[m][n] = __builtin_amdgcn_mfma_f32_16x16x32_f16(af[m], bf[n], acc[m][n], 0, 0, 0);

        if (hn && !nbt) stage_bn_write(nxt);

        __syncthreads();
    }

    // ---- fused sampling epilogue ----
#pragma unroll
    for (int m = 0; m < 2; ++m)
#pragma unroll
        for (int n = 0; n < 4; ++n)
#pragma unroll
            for (int r = 0; r < 4; ++r) {
                int row = bm + (wv >> 1) * 32 + m * 16 + l4 * 4 + r;
                int col = bn + (wv & 1) * 64 + n * 16 + l15;
                float val = acc[m][n][r];
                if (EPI == 2) {
                    if (col & 1) {
                        int s = (col - 1) >> 1;
                        uint32_t e = (uint32_t)(row * 2048 + s);
                        float p = sigmoidf_(val + bias[col]);
                        float u = tf_uniform01(rk0, rk1, e);
                        O0[(size_t)row * 4096 + col] = (u < p) ? F16_ONE : (short)0;
                    } else {
                        O0[(size_t)row * 4096 + col] =
                            (occ[(size_t)row * 2048 + (col >> 1)] != 0.0f) ? F16_ONE : (short)0;
                    }
                } else {
                    size_t e = (size_t)row * 4096 + col;
                    float p = sigmoidf_(val + bias[col]);
                    float u = tf_uniform01(rk0, rk1, (uint32_t)e);
                    short sv = (u < p) ? F16_ONE : (short)0;
                    O0[e] = sv;
                    if (EPI == 1) O1[e] = sv;
                }
            }
}

// =====================================================================
// Gradient GEMM (exact): Out[i,j] = (sum_b Xn Yn - Xp Yp)/1024, fp16 states.
// K-concat 64 steps of 32 b (neg 32, pos 32; pos-Y sign-negated; fp16 -0 ok).
// Fragment-order subtiles with (r ^ subtile) swizzle; reg prefetch.
// tile 128x128, 256 threads = 4 waves (64x64 each)
// =====================================================================
template<int W1MODE>
__global__ __launch_bounds__(256) void grad_mm(
    const short* __restrict__ Xn, const short* __restrict__ Yn,
    const short* __restrict__ Xp, const short* __restrict__ Yp_bf,
    const float* __restrict__ Yp_f32,
    float* __restrict__ Out)
{
    __shared__ __align__(1024) short Xs[2][8 * 512];
    __shared__ __align__(1024) short Ys[2][8 * 512];

    const int tid = threadIdx.x;
    const int bi = blockIdx.y * 128, bj = blockIdx.x * 128;
    const int wv = tid >> 6, lane = tid & 63;
    const int wr = (wv >> 1) * 64, wc = (wv & 1) * 64;
    const int l15 = lane & 15, l4 = lane >> 4;

    const int cg = (tid & 31) * 4;
    const int kg = tid >> 5;
    const int qsub = (tid & 31) >> 2;
    const int koff = (kg >> 1) * 128 + (kg & 1) * 4;

    f32x4 acc[4][4] = {};
    short xr[4][4];
    short yr[4][4];

    auto loadT = [&](int bt) {
        const bool neg = bt < 32;
        const int b0 = (bt & 31) * 32;
        const short* X = neg ? Xn : Xp;
#pragma unroll
        for (int i = 0; i < 4; ++i)
            *(bf16x4*)xr[i] = *(const bf16x4*)(X + (size_t)(b0 + kg * 4 + i) * NH + bi + cg);
        if (W1MODE) {
            if (neg) {
#pragma unroll
                for (int i = 0; i < 4; ++i) {
                    bf16x8 v = *(const bf16x8*)(Yn + (size_t)(b0 + kg * 4 + i) * NV + 2 * (bj + cg));
                    yr[i][0] = v[1]; yr[i][1] = v[3]; yr[i][2] = v[5]; yr[i][3] = v[7];
                }
            } else {
#pragma unroll
                for (int i = 0; i < 4; ++i) {
                    const float* p = Yp_f32 + (size_t)(b0 + kg * 4 + i) * NV + 2 * (bj + cg);
                    f32x4 a = *(const f32x4*)p;
                    f32x4 b = *(const f32x4*)(p + 4);
                    yr[i][0] = (a[1] != 0.0f) ? F16_NEG1 : (short)0;
                    yr[i][1] = (a[3] != 0.0f) ? F16_NEG1 : (short)0;
                    yr[i][2] = (b[1] != 0.0f) ? F16_NEG1 : (short)0;
                    yr[i][3] = (b[3] != 0.0f) ? F16_NEG1 : (short)0;
                }
            }
        } else {
            const short* Y = neg ? Yn : Yp_bf;
            const short sx = neg ? (short)0 : (short)0x8000;
#pragma unroll
            for (int i = 0; i < 4; ++i) {
                bf16x4 v = *(const bf16x4*)(Y + (size_t)(b0 + kg * 4 + i) * NH + bj + cg);
#pragma unroll
                for (int j = 0; j < 4; ++j) yr[i][j] = (short)(v[j] ^ sx);
            }
        }
    };
    auto writeT = [&](int buf) {
#pragma unroll
        for (int j = 0; j < 4; ++j) {
            int r = (tid & 3) * 4 + j;
            int off = qsub * 512 + koff + ((r ^ qsub) & 15) * 8;
            short wx[4] = {xr[0][j], xr[1][j], xr[2][j], xr[3][j]};
            short wy[4] = {yr[0][j], yr[1][j], yr[2][j], yr[3][j]};
            *(bf16x4*)&Xs[buf][off] = *(bf16x4*)wx;
            *(bf16x4*)&Ys[buf][off] = *(bf16x4*)wy;
        }
    };

    loadT(0);
    writeT(0);
    __syncthreads();

    for (int bt = 0; bt < 64; ++bt) {
        const int cur = bt & 1;
        if (bt + 1 < 64) loadT(bt + 1);

        f16x8 xf[4], yf[4];
#pragma unroll
        for (int m = 0; m < 4; ++m) {
            int sm = (wv >> 1) * 4 + m;
            xf[m] = *(f16x8*)&Xs[cur][sm * 512 + l4 * 128 + ((l15 ^ sm) & 15) * 8];
        }
#pragma unroll
        for (int n = 0; n < 4; ++n) {
            int sn = (wv & 1) * 4 + n;
            yf[n] = *(f16x8*)&Ys[cur][sn * 512 + l4 * 128 + ((l15 ^ sn) & 15) * 8];
        }
#pragma unroll
        for (int m = 0; m < 4; ++m)
#pragma unroll
            for (int n = 0; n < 4; ++n)
                acc[m][n] = __builtin_amdgcn_mfma_f32_16x16x32_f16(xf[m], yf[n], acc[m][n], 0, 0, 0);

        if (bt + 1 < 64) writeT(cur ^ 1);
        __syncthreads();
    }

    const float invB = 1.0f / 1024.0f;
#pragma unroll
    for (int m = 0; m < 4; ++m)
#pragma unroll
        for (int n = 0; n < 4; ++n)
#pragma unroll
            for (int r = 0; r < 4; ++r) {
                int i_ = bi + wr + m * 16 + l4 * 4 + r;
                int j_ = bj + wc + n * 16 + l15;
                if (W1MODE) {
                    Out[(size_t)i_ * NV + 2 * j_ + 1] = acc[m][n][r] * invB;
                    Out[(size_t)i_ * NV + 2 * j_]     = 0.0f;
                } else {
                    Out[(size_t)i_ * NH + j_] = acc[m][n][r] * invB;
                }
            }
}

// ---------------- small kernels ----------------
__global__ void cvt_kernel(const float* __restrict__ in, short* __restrict__ out, int n)
{
    int e = blockIdx.x * 256 + threadIdx.x;
    if (e < n) out[e] = (in[e] != 0.0f) ? F16_ONE : (short)0;
}

__global__ void dbv_fast(const float* __restrict__ vdata, const short* __restrict__ vneg,
                         float* __restrict__ out)
{
    __shared__ float part[4][64];
    int c = threadIdx.x & 63, rg = threadIdx.x >> 6;
    int s = blockIdx.x * 64 + c;
    float acc = 0.0f;
    for (int b = rg; b < B_SZ; b += 4)
        acc += ((vneg[(size_t)b * NV + 2 * s + 1] != 0) ? 1.0f : 0.0f)
             - vdata[(size_t)b * NV + 2 * s + 1];
    part[rg][c] = acc;
    __syncthreads();
    if (rg == 0) {
        out[2 * s + 1] = (part[0][c] + part[1][c] + part[2][c] + part[3][c]) * (1.0f / 1024.0f);
        out[2 * s] = 0.0f;
    }
}

__global__ void dbh_fast(const short* __restrict__ Xp, const short* __restrict__ Xn,
                         float* __restrict__ out)
{
    __shared__ int part[4][64];
    int c = threadIdx.x & 63, rg = threadIdx.x >> 6;
    int j = blockIdx.x * 64 + c;
    int acc = 0;
    for (int b = rg; b < B_SZ; b += 4)
        acc += (int)(Xn[(size_t)b * NH + j] != 0) - (int)(Xp[(size_t)b * NH + j] != 0);
    part[rg][c] = acc;
    __syncthreads();
    if (rg == 0)
        out[j] = (float)(part[0][c] + part[1][c] + part[2][c] + part[3][c]) * (1.0f / 1024.0f);
}

__global__ void zero_kernel(unsigned* p) { *p = 0u; }

__global__ void loss_count2(const float* __restrict__ vdata,
                            const short* __restrict__ vneg, unsigned* cnt)
{
    __shared__ int part[4];
    int t = blockIdx.x * 256 + threadIdx.x;
    int local = 0;
#pragma unroll
    for (int it = 0; it < 8; ++it) {
        int e = t + it * 262144;
        int b = e >> 11, s = e & 2047;
        float st = vdata[(size_t)b * NV + 2 * s + 1];
        float sp = (vneg[(size_t)b * NV + 2 * s + 1] != 0) ? 1.0f : 0.0f;
        local += (st != sp) ? 1 : 0;
    }
#pragma unroll
    for (int off = 32; off; off >>= 1) local += __shfl_down(local, off, 64);
    if ((threadIdx.x & 63) == 0) part[threadIdx.x >> 6] = local;
    __syncthreads();
    if (threadIdx.x == 0)
        atomicAdd(cnt, (unsigned)(part[0] + part[1] + part[2] + part[3]));
}

__global__ void loss_final_kernel(const unsigned* cnt, float* out, float lp, float lm)
{
    float mis = (float)(*cnt);
    float mat = 2097152.0f - mis;
    out[0] = -((mat * lp + mis * lm) * (1.0f / 2097152.0f));
}

// ---------------- host ----------------
extern "C" void kernel_launch(void* const* d_in, const int* in_sizes, int n_in,
                              void* d_out, int out_size, void* d_ws, size_t ws_size,
                              hipStream_t stream)
{
    (void)in_sizes; (void)n_in; (void)out_size; (void)ws_size;
    const float* v_data = (const float*)d_in[0];
    const float* occ    = (const float*)d_in[1];
    const float* W1     = (const float*)d_in[2];
    const float* b_v    = (const float*)d_in[3];
    const float* b_h1   = (const float*)d_in[4];
    const float* W2     = (const float*)d_in[5];
    const float* b_h2   = (const float*)d_in[6];
    float* out = (float*)d_out;

    char* w = (char*)d_ws;
    short* vneg = (short*)w;
    short* h1d  = vneg + (size_t)B_SZ * NV;
    short* h2d  = h1d  + (size_t)B_SZ * NH;
    short* h1c  = h2d  + (size_t)B_SZ * NH;
    short* h2n  = h1c  + (size_t)B_SZ * NH;
    unsigned* cnt = (unsigned*)(h2n + (size_t)B_SZ * NH);

    // d_out doubles as fp16 weight scratch during the forward phase
    // (fully overwritten by gradient kernels afterwards).
    short* W1f = (short*)(((uintptr_t)(out + 1) + 15) & ~(uintptr_t)15);
    short* W2f = W1f + (size_t)NH * NV;

    // ---- JAX key derivation ----
    const uint32_t r0 = 0u, r1 = 42u;
    uint32_t kp1a, kp1b, kp2a, kp2b, kfa, kfb, kla, klb;
    tf2x32(r0, r1, 0u, 0u, kp1a, kp1b);
    tf2x32(r0, r1, 0u, 1u, kp2a, kp2b);
    tf2x32(r0, r1, 0u, 2u, kfa, kfb);
    tf2x32(r0, r1, 0u, 3u, kla, klb);
    uint32_t kaA[2], kaB[2], kbA[2], kbB[2], kcA[2], kcB[2];
    for (int i = 0; i < 2; ++i) {
        uint32_t fa, fb;
        tf2x32(kla, klb, 0u, (uint32_t)i, fa, fb);
        tf2x32(fa, fb, 0u, 0u, kaA[i], kaB[i]);
        tf2x32(fa, fb, 0u, 1u, kbA[i], kbB[i]);
        tf2x32(fa, fb, 0u, 2u, kcA[i], kcB[i]);
    }

    const int T = 256;
    const int NELEM = B_SZ * NH;
    dim3 gMM(256);                         // 1-D, XCD-swizzled inside

    conv_f16<<<(NH * NV) / (4 * 256), 256, 0, stream>>>(W1, W1f);
    conv_f16<<<(NH * NH) / (4 * 256), 256, 0, stream>>>(W2, W2f);

    cvt_kernel<<<NELEM / T, T, 0, stream>>>(v_data, vneg, NELEM);

    // positive phase
    mm_fast<0, 0><<<gMM, 512, 0, stream>>>(vneg, nullptr, W1f, nullptr,
                                           b_h1, nullptr, h1d, nullptr, kp1a, kp1b);
    mm_fast<1, 0><<<gMM, 512, 0, stream>>>(h1d, nullptr, W2f, nullptr,
                                           b_h2, nullptr, h2d, h2n, kp2a, kp2b);

    // Gibbs loop (k = 2)
    for (int i = 0; i < 2; ++i) {
        mm_fast<0, 1><<<gMM, 512, 0, stream>>>(vneg, h2n, W1f, W2f,
                                               b_h1, nullptr, h1c, nullptr, kaA[i], kaB[i]);
        mm_fast<0, 0><<<gMM, 512, 0, stream>>>(h1c, nullptr, W2f, nullptr,
                                               b_h2, nullptr, h2n, nullptr, kbA[i], kbB[i]);
        mm_fast<2, 2><<<gMM, 512, 0, stream>>>(h1c, nullptr, W1f, nullptr,
                                               b_v, occ, vneg, nullptr, kcA[i], kcB[i]);
    }

    // final hidden refresh
    mm_fast<0, 1><<<gMM, 512, 0, stream>>>(vneg, h2n, W1f, W2f,
                                           b_h1, nullptr, h1c, nullptr, kfa, kfb);

    // outputs (weight scratch dead after this point)
    float* dW1o  = out + 1;
    float* dbvo  = dW1o + (size_t)NH * NV;
    float* dbh1o = dbvo + NV;
    float* dW2o  = dbh1o + NH;
    float* dbh2o = dW2o + (size_t)NH * NH;

    grad_mm<1><<<dim3(NSGN / 128, NH / 128), T, 0, stream>>>(h1c, vneg, h1d, (short*)nullptr, v_data, dW1o);
    grad_mm<0><<<dim3(NH / 128, NH / 128), T, 0, stream>>>(h1c, h2n, h1d, h2d, (const float*)nullptr, dW2o);
    dbv_fast<<<NSGN / 64, T, 0, stream>>>(v_data, vneg, dbvo);
    dbh_fast<<<NH / 64, T, 0, stream>>>(h1d, h1c, dbh1o);
    dbh_fast<<<NH / 64, T, 0, stream>>>(h2d, h2n, dbh2o);

    zero_kernel<<<1, 1, 0, stream>>>(cnt);
    loss_count2<<<1024, T, 0, stream>>>(v_data, vneg, cnt);
    loss_final_kernel<<<1, 1, 0, stream>>>(cnt, out, logf(1.0f + 1e-7f), logf(1e-7f));
}

// Round 7
// 1789.095 us; speedup vs baseline: 1.3464x; 1.1050x over previous
//
#include <hip/hip_runtime.h>
#include <stdint.h>
#include <math.h>

#define B_SZ 1024
#define NV   4096
#define NH   4096
#define NSGN 2048

typedef short bf16x8 __attribute__((ext_vector_type(8)));
typedef short bf16x4 __attribute__((ext_vector_type(4)));
typedef float f32x4  __attribute__((ext_vector_type(4)));
typedef _Float16 f16x8 __attribute__((ext_vector_type(8)));

#define F16_ONE  ((short)0x3C00)
#define F16_NEG1 ((short)0xBC00)

// ---------------- threefry2x32 (JAX-compatible, 20 rounds) ----------------
__host__ __device__ __forceinline__ void tf2x32(uint32_t k0, uint32_t k1,
                                                uint32_t x0, uint32_t x1,
                                                uint32_t& o0, uint32_t& o1)
{
    uint32_t k2 = k0 ^ k1 ^ 0x1BD11BDAu;
#define TFR(r) { x0 += x1; x1 = (x1 << (r)) | (x1 >> (32 - (r))); x1 ^= x0; }
    x0 += k0; x1 += k1;
    TFR(13) TFR(15) TFR(26) TFR(6)
    x0 += k1; x1 += k2 + 1u;
    TFR(17) TFR(29) TFR(16) TFR(24)
    x0 += k2; x1 += k0 + 2u;
    TFR(13) TFR(15) TFR(26) TFR(6)
    x0 += k0; x1 += k1 + 3u;
    TFR(17) TFR(29) TFR(16) TFR(24)
    x0 += k1; x1 += k2 + 4u;
    TFR(13) TFR(15) TFR(26) TFR(6)
    x0 += k2; x1 += k0 + 5u;
#undef TFR
    o0 = x0; o1 = x1;
}

__device__ __forceinline__ float tf_uniform01(uint32_t k0, uint32_t k1, uint32_t idx)
{
    uint32_t a, b;
    tf2x32(k0, k1, 0u, idx, a, b);
    uint32_t bits = a ^ b;
    uint32_t fb = (bits >> 9) | 0x3F800000u;
    return __uint_as_float(fb) - 1.0f;
}

__device__ __forceinline__ float sigmoidf_(float x)
{
    if (x >= 0.0f) { float e = expf(-x); return 1.0f / (1.0f + e); }
    float e = expf(x); return e / (1.0f + e);
}

__device__ __forceinline__ void gl16(const void* g, void* l)
{
    __builtin_amdgcn_global_load_lds((const __attribute__((address_space(1))) void*)g,
                                     (__attribute__((address_space(3))) void*)l, 16, 0, 0);
}

__device__ __forceinline__ void wait_vmcnt(int n)
{
    switch (n) {
    case 0:  asm volatile("s_waitcnt vmcnt(0)"  ::: "memory"); break;
    case 3:  asm volatile("s_waitcnt vmcnt(3)"  ::: "memory"); break;
    case 5:  asm volatile("s_waitcnt vmcnt(5)"  ::: "memory"); break;
    case 6:  asm volatile("s_waitcnt vmcnt(6)"  ::: "memory"); break;
    case 8:  asm volatile("s_waitcnt vmcnt(8)"  ::: "memory"); break;
    default: asm volatile("s_waitcnt vmcnt(10)" ::: "memory"); break;
    }
}

// ---------------- weight precompute: fp32 -> fp16 (RNE) ----------------
__global__ __launch_bounds__(256) void conv_f16(const float* __restrict__ W,
                                                short* __restrict__ Wf)
{
    size_t i = ((size_t)blockIdx.x * 256 + threadIdx.x) * 4;
    f32x4 v = *(const f32x4*)(W + i);
    short h[4];
#pragma unroll
    for (int c = 0; c < 4; ++c) {
        union { _Float16 f; short s; } u;
        u.f = (_Float16)v[c];
        h[c] = u.s;
    }
    *(bf16x4*)(Wf + i) = *(bf16x4*)h;
}

// =====================================================================
// Fused fp16 GEMM + sampling, counted-vmcnt depth-2 pipeline (T3+T4).
// 64(M) x 128(N) tile, 256 thr = 4 waves, 4 LDS buffers (48 KB), grid 512
// (2 blocks/CU). XCD-swizzled: XCD x owns bn panels {4x..4x+3} (B slice = 4MB).
// Subtiles (16 rows x 32 k) in MFMA-fragment order (slot L = row L&15,
// kchunk L>>4); bt = gl16 direct; bn = reg loads early + XOR ds_write late.
// vmem counts/stage: bt=3, bn=5; waits use c(t+1)+c(t+2), never drain to 0.
//  MODE 0: K=4096 bt.  MODE 1: K=8192 concat (bt then bn).  MODE 2: K=4096 bn.
//  EPI 0: bern -> O0.  EPI 1: dual write.  EPI 2: sign sampling (vneg).
// =====================================================================
template<int EPI, int MODE>
__global__ __launch_bounds__(256, 2) void mm_fast(
    const short* __restrict__ A0, const short* __restrict__ A1,
    const short* __restrict__ B0, const short* __restrict__ B1,
    const float* __restrict__ bias, const float* __restrict__ occ,
    short* __restrict__ O0, short* __restrict__ O1,
    uint32_t rk0, uint32_t rk1)
{
    __shared__ __align__(1024) short As[4][4 * 512];
    __shared__ __align__(1024) short Bs[4][8 * 512];

    const int bid = blockIdx.x;
    const int xcd = bid & 7, slot = bid >> 3;
    const int bn = (xcd * 4 + (slot & 3)) * 128;
    const int bm = (slot >> 2) * 64;

    const int tid = threadIdx.x;
    const int wv = tid >> 6, lane = tid & 63;
    const int l15 = lane & 15, l4 = lane >> 4;
    const int fr = l15, fc = l4 * 8;          // fragment-order source coords
    const int cg = (tid & 31) * 4;            // bn: col base
    const int kg = tid >> 5;                  // bn: k-group (0..7)
    const int qsub = (tid & 31) >> 2;         // bn: subtile
    const int koff = (kg >> 1) * 128 + (kg & 1) * 4;

    f32x4 acc[2][4] = {};
    short rbE[4][4], rbO[4][4];               // bn B staging regs (even/odd stages)

    const int NSTEPS = (MODE == 1) ? 256 : 128;
    auto is_bt  = [&](int t) { return (MODE == 0) || (MODE == 1 && t < 128); };
    auto cnt_of = [&](int s) -> int {
        if (MODE == 0) return 3;
        if (MODE == 2) return 5;
        return (s < 128) ? 3 : 5;
    };

    auto stage_bt = [&](int buf, int kk) {
        gl16(A0 + (size_t)(bm + wv * 16 + fr) * 4096 + kk + fc, &As[buf][wv * 512]);
        gl16(B0 + (size_t)(bn + (wv * 2 + 0) * 16 + fr) * 4096 + kk + fc, &Bs[buf][(wv * 2 + 0) * 512]);
        gl16(B0 + (size_t)(bn + (wv * 2 + 1) * 16 + fr) * 4096 + kk + fc, &Bs[buf][(wv * 2 + 1) * 512]);
    };
    auto stage_bn_load = [&](int buf, int kk, short (&tb)[4][4]) {
        const short* A = (MODE == 1) ? A1 : A0;
        const short* B = (MODE == 1) ? B1 : B0;
#pragma unroll
        for (int i = 0; i < 4; ++i)
            *(bf16x4*)tb[i] = *(const bf16x4*)(B + (size_t)(kk + kg * 4 + i) * 4096 + bn + cg);
        gl16(A + (size_t)(bm + wv * 16 + fr) * 4096 + kk + fc, &As[buf][wv * 512]);
    };
    auto stage_bn_write = [&](int buf, short (&tb)[4][4]) {
#pragma unroll
        for (int j = 0; j < 4; ++j) {
            int r = (tid & 3) * 4 + j;
            int off = qsub * 512 + koff + ((r ^ qsub) & 15) * 8;
            short w4[4] = { tb[0][j], tb[1][j], tb[2][j], tb[3][j] };
            *(bf16x4*)&Bs[buf][off] = *(bf16x4*)w4;
        }
    };

    auto compute = [&](int buf, bool cbt) {
        f16x8 af[2], bf[4];
#pragma unroll
        for (int m = 0; m < 2; ++m)
            af[m] = *(f16x8*)&As[buf][((wv >> 1) * 2 + m) * 512 + lane * 8];
#pragma unroll
        for (int n = 0; n < 4; ++n) {
            int sn = (wv & 1) * 4 + n;
            int off = cbt ? sn * 512 + lane * 8
                          : sn * 512 + l4 * 128 + ((l15 ^ sn) & 15) * 8;
            bf[n] = *(f16x8*)&Bs[buf][off];
        }
#pragma unroll
        for (int m = 0; m < 2; ++m)
#pragma unroll
            for (int n = 0; n < 4; ++n)
                acc[m][n] = __builtin_amdgcn_mfma_f32_16x16x32_f16(af[m], bf[n], acc[m][n], 0, 0, 0);
    };

    auto body = [&](int t, short (&rbI)[4][4], short (&rbW)[4][4]) {
        // A) issue stage t+2
        if (t + 2 < NSTEPS) {
            int kk = ((t + 2) * 32) & 4095;
            if (is_bt(t + 2)) stage_bt((t + 2) & 3, kk);
            else              stage_bn_load((t + 2) & 3, kk, rbI);
        }
        // B) counted wait: stage t complete (t+1, t+2 still in flight)
        int w = 0;
        if (t + 2 < NSTEPS)      w = cnt_of(t + 1) + cnt_of(t + 2);
        else if (t + 1 < NSTEPS) w = cnt_of(t + 1);
        wait_vmcnt(w);
        asm volatile("s_waitcnt lgkmcnt(0)" ::: "memory");
        __builtin_amdgcn_s_barrier();
        __builtin_amdgcn_sched_barrier(0);
        // E) compute
        compute(t & 3, is_bt(t));
        // F) late ds_write of stage t+1's B (bn only)
        if (t + 1 < NSTEPS && !is_bt(t + 1)) {
            wait_vmcnt((t + 2 < NSTEPS) ? cnt_of(t + 2) : 0);
            stage_bn_write((t + 1) & 3, rbW);
        }
    };

    // prologue: stage 0 (+write if bn), stage 1 (load only)
    if (is_bt(0)) {
        stage_bt(0, 0);
    } else {
        stage_bn_load(0, 0, rbE);
        wait_vmcnt(0);
        stage_bn_write(0, rbE);
    }
    if (is_bt(1)) stage_bt(1, 32);
    else          stage_bn_load(1, 32, rbO);

    for (int t = 0; t < NSTEPS; t += 2) {
        body(t, rbE, rbO);
        body(t + 1, rbO, rbE);
    }

    // ---- fused sampling epilogue ----
#pragma unroll
    for (int m = 0; m < 2; ++m)
#pragma unroll
        for (int n = 0; n < 4; ++n)
#pragma unroll
            for (int r = 0; r < 4; ++r) {
                int row = bm + (wv >> 1) * 32 + m * 16 + l4 * 4 + r;
                int col = bn + (wv & 1) * 64 + n * 16 + l15;
                float val = acc[m][n][r];
                if (EPI == 2) {
                    if (col & 1) {
                        int s = (col - 1) >> 1;
                        uint32_t e = (uint32_t)(row * 2048 + s);
                        float p = sigmoidf_(val + bias[col]);
                        float u = tf_uniform01(rk0, rk1, e);
                        O0[(size_t)row * 4096 + col] = (u < p) ? F16_ONE : (short)0;
                    } else {
                        O0[(size_t)row * 4096 + col] =
                            (occ[(size_t)row * 2048 + (col >> 1)] != 0.0f) ? F16_ONE : (short)0;
                    }
                } else {
                    size_t e = (size_t)row * 4096 + col;
                    float p = sigmoidf_(val + bias[col]);
                    float u = tf_uniform01(rk0, rk1, (uint32_t)e);
                    short sv = (u < p) ? F16_ONE : (short)0;
                    O0[e] = sv;
                    if (EPI == 1) O1[e] = sv;
                }
            }
}

// =====================================================================
// Gradient GEMM (exact): Out[i,j] = (sum_b Xn Yn - Xp Yp)/1024, fp16 states.
// tile 128x128, 256 threads = 4 waves (64x64 each); unchanged from round 6.
// =====================================================================
template<int W1MODE>
__global__ __launch_bounds__(256) void grad_mm(
    const short* __restrict__ Xn, const short* __restrict__ Yn,
    const short* __restrict__ Xp, const short* __restrict__ Yp_bf,
    const float* __restrict__ Yp_f32,
    float* __restrict__ Out)
{
    __shared__ __align__(1024) short Xs[2][8 * 512];
    __shared__ __align__(1024) short Ys[2][8 * 512];

    const int tid = threadIdx.x;
    const int bi = blockIdx.y * 128, bj = blockIdx.x * 128;
    const int wv = tid >> 6, lane = tid & 63;
    const int wr = (wv >> 1) * 64, wc = (wv & 1) * 64;
    const int l15 = lane & 15, l4 = lane >> 4;

    const int cg = (tid & 31) * 4;
    const int kg = tid >> 5;
    const int qsub = (tid & 31) >> 2;
    const int koff = (kg >> 1) * 128 + (kg & 1) * 4;

    f32x4 acc[4][4] = {};
    short xr[4][4];
    short yr[4][4];

    auto loadT = [&](int bt) {
        const bool neg = bt < 32;
        const int b0 = (bt & 31) * 32;
        const short* X = neg ? Xn : Xp;
#pragma unroll
        for (int i = 0; i < 4; ++i)
            *(bf16x4*)xr[i] = *(const bf16x4*)(X + (size_t)(b0 + kg * 4 + i) * NH + bi + cg);
        if (W1MODE) {
            if (neg) {
#pragma unroll
                for (int i = 0; i < 4; ++i) {
                    bf16x8 v = *(const bf16x8*)(Yn + (size_t)(b0 + kg * 4 + i) * NV + 2 * (bj + cg));
                    yr[i][0] = v[1]; yr[i][1] = v[3]; yr[i][2] = v[5]; yr[i][3] = v[7];
                }
            } else {
#pragma unroll
                for (int i = 0; i < 4; ++i) {
                    const float* p = Yp_f32 + (size_t)(b0 + kg * 4 + i) * NV + 2 * (bj + cg);
                    f32x4 a = *(const f32x4*)p;
                    f32x4 b = *(const f32x4*)(p + 4);
                    yr[i][0] = (a[1] != 0.0f) ? F16_NEG1 : (short)0;
                    yr[i][1] = (a[3] != 0.0f) ? F16_NEG1 : (short)0;
                    yr[i][2] = (b[1] != 0.0f) ? F16_NEG1 : (short)0;
                    yr[i][3] = (b[3] != 0.0f) ? F16_NEG1 : (short)0;
                }
            }
        } else {
            const short* Y = neg ? Yn : Yp_bf;
            const short sx = neg ? (short)0 : (short)0x8000;
#pragma unroll
            for (int i = 0; i < 4; ++i) {
                bf16x4 v = *(const bf16x4*)(Y + (size_t)(b0 + kg * 4 + i) * NH + bj + cg);
#pragma unroll
                for (int j = 0; j < 4; ++j) yr[i][j] = (short)(v[j] ^ sx);
            }
        }
    };
    auto writeT = [&](int buf) {
#pragma unroll
        for (int j = 0; j < 4; ++j) {
            int r = (tid & 3) * 4 + j;
            int off = qsub * 512 + koff + ((r ^ qsub) & 15) * 8;
            short wx[4] = {xr[0][j], xr[1][j], xr[2][j], xr[3][j]};
            short wy[4] = {yr[0][j], yr[1][j], yr[2][j], yr[3][j]};
            *(bf16x4*)&Xs[buf][off] = *(bf16x4*)wx;
            *(bf16x4*)&Ys[buf][off] = *(bf16x4*)wy;
        }
    };

    loadT(0);
    writeT(0);
    __syncthreads();

    for (int bt = 0; bt < 64; ++bt) {
        const int cur = bt & 1;
        if (bt + 1 < 64) loadT(bt + 1);

        f16x8 xf[4], yf[4];
#pragma unroll
        for (int m = 0; m < 4; ++m) {
            int sm = (wv >> 1) * 4 + m;
            xf[m] = *(f16x8*)&Xs[cur][sm * 512 + l4 * 128 + ((l15 ^ sm) & 15) * 8];
        }
#pragma unroll
        for (int n = 0; n < 4; ++n) {
            int sn = (wv & 1) * 4 + n;
            yf[n] = *(f16x8*)&Ys[cur][sn * 512 + l4 * 128 + ((l15 ^ sn) & 15) * 8];
        }
#pragma unroll
        for (int m = 0; m < 4; ++m)
#pragma unroll
            for (int n = 0; n < 4; ++n)
                acc[m][n] = __builtin_amdgcn_mfma_f32_16x16x32_f16(xf[m], yf[n], acc[m][n], 0, 0, 0);

        if (bt + 1 < 64) writeT(cur ^ 1);
        __syncthreads();
    }

    const float invB = 1.0f / 1024.0f;
#pragma unroll
    for (int m = 0; m < 4; ++m)
#pragma unroll
        for (int n = 0; n < 4; ++n)
#pragma unroll
            for (int r = 0; r < 4; ++r) {
                int i_ = bi + wr + m * 16 + l4 * 4 + r;
                int j_ = bj + wc + n * 16 + l15;
                if (W1MODE) {
                    Out[(size_t)i_ * NV + 2 * j_ + 1] = acc[m][n][r] * invB;
                    Out[(size_t)i_ * NV + 2 * j_]     = 0.0f;
                } else {
                    Out[(size_t)i_ * NH + j_] = acc[m][n][r] * invB;
                }
            }
}

// ---------------- small kernels ----------------
__global__ void cvt_kernel(const float* __restrict__ in, short* __restrict__ out, int n)
{
    int e = blockIdx.x * 256 + threadIdx.x;
    if (e < n) out[e] = (in[e] != 0.0f) ? F16_ONE : (short)0;
}

__global__ void dbv_fast(const float* __restrict__ vdata, const short* __restrict__ vneg,
                         float* __restrict__ out)
{
    __shared__ float part[4][64];
    int c = threadIdx.x & 63, rg = threadIdx.x >> 6;
    int s = blockIdx.x * 64 + c;
    float acc = 0.0f;
    for (int b = rg; b < B_SZ; b += 4)
        acc += ((vneg[(size_t)b * NV + 2 * s + 1] != 0) ? 1.0f : 0.0f)
             - vdata[(size_t)b * NV + 2 * s + 1];
    part[rg][c] = acc;
    __syncthreads();
    if (rg == 0) {
        out[2 * s + 1] = (part[0][c] + part[1][c] + part[2][c] + part[3][c]) * (1.0f / 1024.0f);
        out[2 * s] = 0.0f;
    }
}

__global__ void dbh_fast(const short* __restrict__ Xp, const short* __restrict__ Xn,
                         float* __restrict__ out)
{
    __shared__ int part[4][64];
    int c = threadIdx.x & 63, rg = threadIdx.x >> 6;
    int j = blockIdx.x * 64 + c;
    int acc = 0;
    for (int b = rg; b < B_SZ; b += 4)
        acc += (int)(Xn[(size_t)b * NH + j] != 0) - (int)(Xp[(size_t)b * NH + j] != 0);
    part[rg][c] = acc;
    __syncthreads();
    if (rg == 0)
        out[j] = (float)(part[0][c] + part[1][c] + part[2][c] + part[3][c]) * (1.0f / 1024.0f);
}

__global__ void zero_kernel(unsigned* p) { *p = 0u; }

__global__ void loss_count2(const float* __restrict__ vdata,
                            const short* __restrict__ vneg, unsigned* cnt)
{
    __shared__ int part[4];
    int t = blockIdx.x * 256 + threadIdx.x;
    int local = 0;
#pragma unroll
    for (int it = 0; it < 8; ++it) {
        int e = t + it * 262144;
        int b = e >> 11, s = e & 2047;
        float st = vdata[(size_t)b * NV + 2 * s + 1];
        float sp = (vneg[(size_t)b * NV + 2 * s + 1] != 0) ? 1.0f : 0.0f;
        local += (st != sp) ? 1 : 0;
    }
#pragma unroll
    for (int off = 32; off; off >>= 1) local += __shfl_down(local, off, 64);
    if ((threadIdx.x & 63) == 0) part[threadIdx.x >> 6] = local;
    __syncthreads();
    if (threadIdx.x == 0)
        atomicAdd(cnt, (unsigned)(part[0] + part[1] + part[2] + part[3]));
}

__global__ void loss_final_kernel(const unsigned* cnt, float* out, float lp, float lm)
{
    float mis = (float)(*cnt);
    float mat = 2097152.0f - mis;
    out[0] = -((mat * lp + mis * lm) * (1.0f / 2097152.0f));
}

// ---------------- host ----------------
extern "C" void kernel_launch(void* const* d_in, const int* in_sizes, int n_in,
                              void* d_out, int out_size, void* d_ws, size_t ws_size,
                              hipStream_t stream)
{
    (void)in_sizes; (void)n_in; (void)out_size; (void)ws_size;
    const float* v_data = (const float*)d_in[0];
    const float* occ    = (const float*)d_in[1];
    const float* W1     = (const float*)d_in[2];
    const float* b_v    = (const float*)d_in[3];
    const float* b_h1   = (const float*)d_in[4];
    const float* W2     = (const float*)d_in[5];
    const float* b_h2   = (const float*)d_in[6];
    float* out = (float*)d_out;

    char* w = (char*)d_ws;
    short* vneg = (short*)w;
    short* h1d  = vneg + (size_t)B_SZ * NV;
    short* h2d  = h1d  + (size_t)B_SZ * NH;
    short* h1c  = h2d  + (size_t)B_SZ * NH;
    short* h2n  = h1c  + (size_t)B_SZ * NH;
    unsigned* cnt = (unsigned*)(h2n + (size_t)B_SZ * NH);

    // d_out doubles as fp16 weight scratch during the forward phase.
    short* W1f = (short*)(((uintptr_t)(out + 1) + 15) & ~(uintptr_t)15);
    short* W2f = W1f + (size_t)NH * NV;

    // ---- JAX key derivation ----
    const uint32_t r0 = 0u, r1 = 42u;
    uint32_t kp1a, kp1b, kp2a, kp2b, kfa, kfb, kla, klb;
    tf2x32(r0, r1, 0u, 0u, kp1a, kp1b);
    tf2x32(r0, r1, 0u, 1u, kp2a, kp2b);
    tf2x32(r0, r1, 0u, 2u, kfa, kfb);
    tf2x32(r0, r1, 0u, 3u, kla, klb);
    uint32_t kaA[2], kaB[2], kbA[2], kbB[2], kcA[2], kcB[2];
    for (int i = 0; i < 2; ++i) {
        uint32_t fa, fb;
        tf2x32(kla, klb, 0u, (uint32_t)i, fa, fb);
        tf2x32(fa, fb, 0u, 0u, kaA[i], kaB[i]);
        tf2x32(fa, fb, 0u, 1u, kbA[i], kbB[i]);
        tf2x32(fa, fb, 0u, 2u, kcA[i], kcB[i]);
    }

    const int T = 256;
    const int NELEM = B_SZ * NH;
    dim3 gMM(512);                         // 16 bm x 32 bn, XCD-swizzled

    conv_f16<<<(NH * NV) / (4 * 256), 256, 0, stream>>>(W1, W1f);
    conv_f16<<<(NH * NH) / (4 * 256), 256, 0, stream>>>(W2, W2f);

    cvt_kernel<<<NELEM / T, T, 0, stream>>>(v_data, vneg, NELEM);

    // positive phase
    mm_fast<0, 0><<<gMM, 256, 0, stream>>>(vneg, nullptr, W1f, nullptr,
                                           b_h1, nullptr, h1d, nullptr, kp1a, kp1b);
    mm_fast<1, 0><<<gMM, 256, 0, stream>>>(h1d, nullptr, W2f, nullptr,
                                           b_h2, nullptr, h2d, h2n, kp2a, kp2b);

    // Gibbs loop (k = 2)
    for (int i = 0; i < 2; ++i) {
        mm_fast<0, 1><<<gMM, 256, 0, stream>>>(vneg, h2n, W1f, W2f,
                                               b_h1, nullptr, h1c, nullptr, kaA[i], kaB[i]);
        mm_fast<0, 0><<<gMM, 256, 0, stream>>>(h1c, nullptr, W2f, nullptr,
                                               b_h2, nullptr, h2n, nullptr, kbA[i], kbB[i]);
        mm_fast<2, 2><<<gMM, 256, 0, stream>>>(h1c, nullptr, W1f, nullptr,
                                               b_v, occ, vneg, nullptr, kcA[i], kcB[i]);
    }

    // final hidden refresh
    mm_fast<0, 1><<<gMM, 256, 0, stream>>>(vneg, h2n, W1f, W2f,
                                           b_h1, nullptr, h1c, nullptr, kfa, kfb);

    // outputs (weight scratch dead after this point)
    float* dW1o  = out + 1;
    float* dbvo  = dW1o + (size_t)NH * NV;
    float* dbh1o = dbvo + NV;
    float* dW2o  = dbh1o + NH;
    float* dbh2o = dW2o + (size_t)NH * NH;

    grad_mm<1><<<dim3(NSGN / 128, NH / 128), T, 0, stream>>>(h1c, vneg, h1d, (short*)nullptr, v_data, dW1o);
    grad_mm<0><<<dim3(NH / 128, NH / 128), T, 0, stream>>>(h1c, h2n, h1d, h2d, (const float*)nullptr, dW2o);
    dbv_fast<<<NSGN / 64, T, 0, stream>>>(v_data, vneg, dbvo);
    dbh_fast<<<NH / 64, T, 0, stream>>>(h1d, h1c, dbh1o);
    dbh_fast<<<NH / 64, T, 0, stream>>>(h2d, h2n, dbh2o);

    zero_kernel<<<1, 1, 0, stream>>>(cnt);
    loss_count2<<<1024, T, 0, stream>>>(v_data, vneg, cnt);
    loss_final_kernel<<<1, 1, 0, stream>>>(cnt, out, logf(1.0f + 1e-7f), logf(1e-7f));
}

// Round 8
// 1684.940 us; speedup vs baseline: 1.4296x; 1.0618x over previous
//
#include <hip/hip_runtime.h>
#include <stdint.h>
#include <math.h>

#define B_SZ 1024
#define NV   4096
#define NH   4096
#define NSGN 2048

typedef short bf16x8 __attribute__((ext_vector_type(8)));
typedef short bf16x4 __attribute__((ext_vector_type(4)));
typedef float f32x4  __attribute__((ext_vector_type(4)));
typedef _Float16 f16x8 __attribute__((ext_vector_type(8)));

#define F16_ONE  ((short)0x3C00)
#define F16_NEG1 ((short)0xBC00)

// ---------------- threefry2x32 (JAX-compatible, 20 rounds) ----------------
__host__ __device__ __forceinline__ void tf2x32(uint32_t k0, uint32_t k1,
                                                uint32_t x0, uint32_t x1,
                                                uint32_t& o0, uint32_t& o1)
{
    uint32_t k2 = k0 ^ k1 ^ 0x1BD11BDAu;
#define TFR(r) { x0 += x1; x1 = (x1 << (r)) | (x1 >> (32 - (r))); x1 ^= x0; }
    x0 += k0; x1 += k1;
    TFR(13) TFR(15) TFR(26) TFR(6)
    x0 += k1; x1 += k2 + 1u;
    TFR(17) TFR(29) TFR(16) TFR(24)
    x0 += k2; x1 += k0 + 2u;
    TFR(13) TFR(15) TFR(26) TFR(6)
    x0 += k0; x1 += k1 + 3u;
    TFR(17) TFR(29) TFR(16) TFR(24)
    x0 += k1; x1 += k2 + 4u;
    TFR(13) TFR(15) TFR(26) TFR(6)
    x0 += k2; x1 += k0 + 5u;
#undef TFR
    o0 = x0; o1 = x1;
}

__device__ __forceinline__ float tf_uniform01(uint32_t k0, uint32_t k1, uint32_t idx)
{
    uint32_t a, b;
    tf2x32(k0, k1, 0u, idx, a, b);
    uint32_t bits = a ^ b;
    uint32_t fb = (bits >> 9) | 0x3F800000u;
    return __uint_as_float(fb) - 1.0f;
}

__device__ __forceinline__ float sigmoidf_(float x)
{
    if (x >= 0.0f) { float e = expf(-x); return 1.0f / (1.0f + e); }
    float e = expf(x); return e / (1.0f + e);
}

__device__ __forceinline__ void gl16(const void* g, void* l)
{
    __builtin_amdgcn_global_load_lds((const __attribute__((address_space(1))) void*)g,
                                     (__attribute__((address_space(3))) void*)l, 16, 0, 0);
}

// ---------------- weight precompute: fp32 -> fp16 direct + transposed ----------------
__global__ __launch_bounds__(256) void conv_tr(const float* __restrict__ W,
                                               short* __restrict__ Wf,
                                               short* __restrict__ Wt)
{
    __shared__ short t[64][65];
    const int bx = blockIdx.x * 64;   // col base
    const int by = blockIdx.y * 64;   // row base
    const int r0 = threadIdx.x >> 4;          // 0..15
    const int c0 = (threadIdx.x & 15) * 4;    // 0..60
#pragma unroll
    for (int i = 0; i < 4; ++i) {
        int row = by + r0 + i * 16;
        f32x4 v = *(const f32x4*)(W + (size_t)row * 4096 + bx + c0);
        short h[4];
#pragma unroll
        for (int j = 0; j < 4; ++j) {
            union { _Float16 f; short s; } u;
            u.f = (_Float16)v[j];
            h[j] = u.s;
        }
        *(bf16x4*)(Wf + (size_t)row * 4096 + bx + c0) = *(bf16x4*)h;
#pragma unroll
        for (int j = 0; j < 4; ++j) t[c0 + j][r0 + i * 16] = h[j];
    }
    __syncthreads();
#pragma unroll
    for (int i = 0; i < 4; ++i) {
        int orow = r0 + i * 16;   // output row = original col
        short o[4] = { t[orow][c0], t[orow][c0 + 1], t[orow][c0 + 2], t[orow][c0 + 3] };
        *(bf16x4*)(Wt + (size_t)(bx + orow) * 4096 + by + c0) = *(bf16x4*)o;
    }
}

// =====================================================================
// Fused fp16 bt-GEMM + sampling. All operands [n][k] row-major (weights
// pre-transposed where needed) -> pure global_load_lds staging.
// Tile 64(M) x 128(N), BK=64, 512 thr = 8 waves (2M x 4N of 32x32), dbuf
// 48 KB LDS, grid 512 = 2 blocks/CU (16 waves/CU). Subtiles (16r x 32k)
// in MFMA fragment order (slot L = row L&15, kchunk L>>4), gl16 direct.
//  MODE 0: K=4096 (A0,B0).  MODE 1: K=8192 concat (A0,B0 then A1,B1).
//  EPI 0: bern -> O0.  EPI 1: dual write.  EPI 2: sign sampling (vneg).
// XCD-swizzled: XCD x owns bn panels {4x..4x+3} (B slice = 4 MB = L2).
// =====================================================================
template<int EPI, int MODE>
__global__ __launch_bounds__(512, 4) void mm_fast(
    const short* __restrict__ A0, const short* __restrict__ A1,
    const short* __restrict__ B0, const short* __restrict__ B1,
    const float* __restrict__ bias, const float* __restrict__ occ,
    short* __restrict__ O0, short* __restrict__ O1,
    uint32_t rk0, uint32_t rk1)
{
    __shared__ __align__(1024) short As[2][8 * 512];
    __shared__ __align__(1024) short Bs[2][16 * 512];

    const int bid = blockIdx.x;
    const int xcd = bid & 7, slot = bid >> 3;
    const int bn = (xcd * 4 + (slot & 3)) * 128;
    const int bm = (slot >> 2) * 64;

    const int tid = threadIdx.x;
    const int wv = tid >> 6, lane = tid & 63;
    const int l15 = lane & 15, l4 = lane >> 4;
    const int fr = l15, fc = l4 * 8;      // fragment-order source coords
    const int wm = wv >> 2, wn = wv & 3;  // output region split 2(M) x 4(N)

    f32x4 acc[2][2] = {};

    const int NT = (MODE == 1) ? 128 : 64;

    auto stage = [&](int buf, int t) {
        const short* A = (MODE == 1 && t >= 64) ? A1 : A0;
        const short* B = (MODE == 1 && t >= 64) ? B1 : B0;
        const int kk = (t & 63) * 64;
        // A: 8 subtiles (kc*4 + msub), one per wave
        gl16(A + (size_t)(bm + (wv & 3) * 16 + fr) * 4096 + kk + (wv >> 2) * 32 + fc,
             &As[buf][wv * 512]);
        // B: 16 subtiles (kc*8 + nsub), two per wave
        const short* brow = B + (size_t)(bn + wv * 16 + fr) * 4096 + kk + fc;
        gl16(brow,      &Bs[buf][wv * 512]);
        gl16(brow + 32, &Bs[buf][(wv + 8) * 512]);
    };

    auto compute = [&](int buf) {
        f16x8 af[2][2], bfr[2][2];
#pragma unroll
        for (int kc = 0; kc < 2; ++kc)
#pragma unroll
            for (int m = 0; m < 2; ++m)
                af[m][kc] = *(f16x8*)&As[buf][(kc * 4 + wm * 2 + m) * 512 + lane * 8];
#pragma unroll
        for (int kc = 0; kc < 2; ++kc)
#pragma unroll
            for (int n = 0; n < 2; ++n)
                bfr[n][kc] = *(f16x8*)&Bs[buf][(kc * 8 + wn * 2 + n) * 512 + lane * 8];
#pragma unroll
        for (int m = 0; m < 2; ++m)
#pragma unroll
            for (int n = 0; n < 2; ++n) {
                acc[m][n] = __builtin_amdgcn_mfma_f32_16x16x32_f16(af[m][0], bfr[n][0], acc[m][n], 0, 0, 0);
                acc[m][n] = __builtin_amdgcn_mfma_f32_16x16x32_f16(af[m][1], bfr[n][1], acc[m][n], 0, 0, 0);
            }
    };

    stage(0, 0);
    __syncthreads();
    for (int t = 0; t < NT; ++t) {
        const int cur = t & 1;
        if (t + 1 < NT) stage(cur ^ 1, t + 1);
        compute(cur);
        __syncthreads();
    }

    // ---- fused sampling epilogue ----
#pragma unroll
    for (int m = 0; m < 2; ++m)
#pragma unroll
        for (int n = 0; n < 2; ++n)
#pragma unroll
            for (int r = 0; r < 4; ++r) {
                int row = bm + wm * 32 + m * 16 + l4 * 4 + r;
                int col = bn + wn * 32 + n * 16 + l15;
                float val = acc[m][n][r];
                if (EPI == 2) {
                    if (col & 1) {
                        int s = (col - 1) >> 1;
                        uint32_t e = (uint32_t)(row * 2048 + s);
                        float p = sigmoidf_(val + bias[col]);
                        float u = tf_uniform01(rk0, rk1, e);
                        O0[(size_t)row * 4096 + col] = (u < p) ? F16_ONE : (short)0;
                    } else {
                        O0[(size_t)row * 4096 + col] =
                            (occ[(size_t)row * 2048 + (col >> 1)] != 0.0f) ? F16_ONE : (short)0;
                    }
                } else {
                    size_t e = (size_t)row * 4096 + col;
                    float p = sigmoidf_(val + bias[col]);
                    float u = tf_uniform01(rk0, rk1, (uint32_t)e);
                    short sv = (u < p) ? F16_ONE : (short)0;
                    O0[e] = sv;
                    if (EPI == 1) O1[e] = sv;
                }
            }
}

// =====================================================================
// Gradient GEMM (exact): Out[i,j] = (sum_b Xn Yn - Xp Yp)/1024, fp16 states.
// tile 128x128, 256 threads = 4 waves (64x64 each); unchanged.
// =====================================================================
template<int W1MODE>
__global__ __launch_bounds__(256) void grad_mm(
    const short* __restrict__ Xn, const short* __restrict__ Yn,
    const short* __restrict__ Xp, const short* __restrict__ Yp_bf,
    const float* __restrict__ Yp_f32,
    float* __restrict__ Out)
{
    __shared__ __align__(1024) short Xs[2][8 * 512];
    __shared__ __align__(1024) short Ys[2][8 * 512];

    const int tid = threadIdx.x;
    const int bi = blockIdx.y * 128, bj = blockIdx.x * 128;
    const int wv = tid >> 6, lane = tid & 63;
    const int wr = (wv >> 1) * 64, wc = (wv & 1) * 64;
    const int l15 = lane & 15, l4 = lane >> 4;

    const int cg = (tid & 31) * 4;
    const int kg = tid >> 5;
    const int qsub = (tid & 31) >> 2;
    const int koff = (kg >> 1) * 128 + (kg & 1) * 4;

    f32x4 acc[4][4] = {};
    short xr[4][4];
    short yr[4][4];

    auto loadT = [&](int bt) {
        const bool neg = bt < 32;
        const int b0 = (bt & 31) * 32;
        const short* X = neg ? Xn : Xp;
#pragma unroll
        for (int i = 0; i < 4; ++i)
            *(bf16x4*)xr[i] = *(const bf16x4*)(X + (size_t)(b0 + kg * 4 + i) * NH + bi + cg);
        if (W1MODE) {
            if (neg) {
#pragma unroll
                for (int i = 0; i < 4; ++i) {
                    bf16x8 v = *(const bf16x8*)(Yn + (size_t)(b0 + kg * 4 + i) * NV + 2 * (bj + cg));
                    yr[i][0] = v[1]; yr[i][1] = v[3]; yr[i][2] = v[5]; yr[i][3] = v[7];
                }
            } else {
#pragma unroll
                for (int i = 0; i < 4; ++i) {
                    const float* p = Yp_f32 + (size_t)(b0 + kg * 4 + i) * NV + 2 * (bj + cg);
                    f32x4 a = *(const f32x4*)p;
                    f32x4 b = *(const f32x4*)(p + 4);
                    yr[i][0] = (a[1] != 0.0f) ? F16_NEG1 : (short)0;
                    yr[i][1] = (a[3] != 0.0f) ? F16_NEG1 : (short)0;
                    yr[i][2] = (b[1] != 0.0f) ? F16_NEG1 : (short)0;
                    yr[i][3] = (b[3] != 0.0f) ? F16_NEG1 : (short)0;
                }
            }
        } else {
            const short* Y = neg ? Yn : Yp_bf;
            const short sx = neg ? (short)0 : (short)0x8000;
#pragma unroll
            for (int i = 0; i < 4; ++i) {
                bf16x4 v = *(const bf16x4*)(Y + (size_t)(b0 + kg * 4 + i) * NH + bj + cg);
#pragma unroll
                for (int j = 0; j < 4; ++j) yr[i][j] = (short)(v[j] ^ sx);
            }
        }
    };
    auto writeT = [&](int buf) {
#pragma unroll
        for (int j = 0; j < 4; ++j) {
            int r = (tid & 3) * 4 + j;
            int off = qsub * 512 + koff + ((r ^ qsub) & 15) * 8;
            short wx[4] = {xr[0][j], xr[1][j], xr[2][j], xr[3][j]};
            short wy[4] = {yr[0][j], yr[1][j], yr[2][j], yr[3][j]};
            *(bf16x4*)&Xs[buf][off] = *(bf16x4*)wx;
            *(bf16x4*)&Ys[buf][off] = *(bf16x4*)wy;
        }
    };

    loadT(0);
    writeT(0);
    __syncthreads();

    for (int bt = 0; bt < 64; ++bt) {
        const int cur = bt & 1;
        if (bt + 1 < 64) loadT(bt + 1);

        f16x8 xf[4], yf[4];
#pragma unroll
        for (int m = 0; m < 4; ++m) {
            int sm = (wv >> 1) * 4 + m;
            xf[m] = *(f16x8*)&Xs[cur][sm * 512 + l4 * 128 + ((l15 ^ sm) & 15) * 8];
        }
#pragma unroll
        for (int n = 0; n < 4; ++n) {
            int sn = (wv & 1) * 4 + n;
            yf[n] = *(f16x8*)&Ys[cur][sn * 512 + l4 * 128 + ((l15 ^ sn) & 15) * 8];
        }
#pragma unroll
        for (int m = 0; m < 4; ++m)
#pragma unroll
            for (int n = 0; n < 4; ++n)
                acc[m][n] = __builtin_amdgcn_mfma_f32_16x16x32_f16(xf[m], yf[n], acc[m][n], 0, 0, 0);

        if (bt + 1 < 64) writeT(cur ^ 1);
        __syncthreads();
    }

    const float invB = 1.0f / 1024.0f;
#pragma unroll
    for (int m = 0; m < 4; ++m)
#pragma unroll
        for (int n = 0; n < 4; ++n)
#pragma unroll
            for (int r = 0; r < 4; ++r) {
                int i_ = bi + wr + m * 16 + l4 * 4 + r;
                int j_ = bj + wc + n * 16 + l15;
                if (W1MODE) {
                    Out[(size_t)i_ * NV + 2 * j_ + 1] = acc[m][n][r] * invB;
                    Out[(size_t)i_ * NV + 2 * j_]     = 0.0f;
                } else {
                    Out[(size_t)i_ * NH + j_] = acc[m][n][r] * invB;
                }
            }
}

// ---------------- small kernels ----------------
__global__ void cvt_kernel(const float* __restrict__ in, short* __restrict__ out, int n)
{
    int e = blockIdx.x * 256 + threadIdx.x;
    if (e < n) out[e] = (in[e] != 0.0f) ? F16_ONE : (short)0;
}

__global__ void dbv_fast(const float* __restrict__ vdata, const short* __restrict__ vneg,
                         float* __restrict__ out)
{
    __shared__ float part[4][64];
    int c = threadIdx.x & 63, rg = threadIdx.x >> 6;
    int s = blockIdx.x * 64 + c;
    float acc = 0.0f;
    for (int b = rg; b < B_SZ; b += 4)
        acc += ((vneg[(size_t)b * NV + 2 * s + 1] != 0) ? 1.0f : 0.0f)
             - vdata[(size_t)b * NV + 2 * s + 1];
    part[rg][c] = acc;
    __syncthreads();
    if (rg == 0) {
        out[2 * s + 1] = (part[0][c] + part[1][c] + part[2][c] + part[3][c]) * (1.0f / 1024.0f);
        out[2 * s] = 0.0f;
    }
}

__global__ void dbh_fast(const short* __restrict__ Xp, const short* __restrict__ Xn,
                         float* __restrict__ out)
{
    __shared__ int part[4][64];
    int c = threadIdx.x & 63, rg = threadIdx.x >> 6;
    int j = blockIdx.x * 64 + c;
    int acc = 0;
    for (int b = rg; b < B_SZ; b += 4)
        acc += (int)(Xn[(size_t)b * NH + j] != 0) - (int)(Xp[(size_t)b * NH + j] != 0);
    part[rg][c] = acc;
    __syncthreads();
    if (rg == 0)
        out[j] = (float)(part[0][c] + part[1][c] + part[2][c] + part[3][c]) * (1.0f / 1024.0f);
}

__global__ void zero_kernel(unsigned* p) { *p = 0u; }

__global__ void loss_count2(const float* __restrict__ vdata,
                            const short* __restrict__ vneg, unsigned* cnt)
{
    __shared__ int part[4];
    int t = blockIdx.x * 256 + threadIdx.x;
    int local = 0;
#pragma unroll
    for (int it = 0; it < 8; ++it) {
        int e = t + it * 262144;
        int b = e >> 11, s = e & 2047;
        float st = vdata[(size_t)b * NV + 2 * s + 1];
        float sp = (vneg[(size_t)b * NV + 2 * s + 1] != 0) ? 1.0f : 0.0f;
        local += (st != sp) ? 1 : 0;
    }
#pragma unroll
    for (int off = 32; off; off >>= 1) local += __shfl_down(local, off, 64);
    if ((threadIdx.x & 63) == 0) part[threadIdx.x >> 6] = local;
    __syncthreads();
    if (threadIdx.x == 0)
        atomicAdd(cnt, (unsigned)(part[0] + part[1] + part[2] + part[3]));
}

__global__ void loss_final_kernel(const unsigned* cnt, float* out, float lp, float lm)
{
    float mis = (float)(*cnt);
    float mat = 2097152.0f - mis;
    out[0] = -((mat * lp + mis * lm) * (1.0f / 2097152.0f));
}

// ---------------- host ----------------
extern "C" void kernel_launch(void* const* d_in, const int* in_sizes, int n_in,
                              void* d_out, int out_size, void* d_ws, size_t ws_size,
                              hipStream_t stream)
{
    (void)in_sizes; (void)n_in; (void)out_size; (void)ws_size;
    const float* v_data = (const float*)d_in[0];
    const float* occ    = (const float*)d_in[1];
    const float* W1     = (const float*)d_in[2];
    const float* b_v    = (const float*)d_in[3];
    const float* b_h1   = (const float*)d_in[4];
    const float* W2     = (const float*)d_in[5];
    const float* b_h2   = (const float*)d_in[6];
    float* out = (float*)d_out;

    char* w = (char*)d_ws;
    short* vneg = (short*)w;
    short* h1d  = vneg + (size_t)B_SZ * NV;
    short* h2d  = h1d  + (size_t)B_SZ * NH;
    short* h1c  = h2d  + (size_t)B_SZ * NH;
    short* h2n  = h1c  + (size_t)B_SZ * NH;
    unsigned* cnt = (unsigned*)(h2n + (size_t)B_SZ * NH);

    // d_out doubles as fp16 weight scratch (4 x 32 MB = 128 MB of the
    // 134 MB output; fully overwritten by gradient kernels afterwards).
    short* W1f = (short*)(((uintptr_t)(out + 1) + 15) & ~(uintptr_t)15);
    short* W1T = W1f + (size_t)NH * NV;
    short* W2f = W1T + (size_t)NH * NV;
    short* W2T = W2f + (size_t)NH * NH;

    // ---- JAX key derivation ----
    const uint32_t r0 = 0u, r1 = 42u;
    uint32_t kp1a, kp1b, kp2a, kp2b, kfa, kfb, kla, klb;
    tf2x32(r0, r1, 0u, 0u, kp1a, kp1b);
    tf2x32(r0, r1, 0u, 1u, kp2a, kp2b);
    tf2x32(r0, r1, 0u, 2u, kfa, kfb);
    tf2x32(r0, r1, 0u, 3u, kla, klb);
    uint32_t kaA[2], kaB[2], kbA[2], kbB[2], kcA[2], kcB[2];
    for (int i = 0; i < 2; ++i) {
        uint32_t fa, fb;
        tf2x32(kla, klb, 0u, (uint32_t)i, fa, fb);
        tf2x32(fa, fb, 0u, 0u, kaA[i], kaB[i]);
        tf2x32(fa, fb, 0u, 1u, kbA[i], kbB[i]);
        tf2x32(fa, fb, 0u, 2u, kcA[i], kcB[i]);
    }

    const int T = 256;
    const int NELEM = B_SZ * NH;
    dim3 gMM(512);                       // 16 bm x 32 bn, XCD-swizzled
    dim3 gTr(64, 64);

    conv_tr<<<gTr, 256, 0, stream>>>(W1, W1f, W1T);
    conv_tr<<<gTr, 256, 0, stream>>>(W2, W2f, W2T);

    cvt_kernel<<<NELEM / T, T, 0, stream>>>(v_data, vneg, NELEM);

    // positive phase
    mm_fast<0, 0><<<gMM, 512, 0, stream>>>(vneg, nullptr, W1f, nullptr,
                                           b_h1, nullptr, h1d, nullptr, kp1a, kp1b);
    mm_fast<1, 0><<<gMM, 512, 0, stream>>>(h1d, nullptr, W2f, nullptr,
                                           b_h2, nullptr, h2d, h2n, kp2a, kp2b);

    // Gibbs loop (k = 2)
    for (int i = 0; i < 2; ++i) {
        mm_fast<0, 1><<<gMM, 512, 0, stream>>>(vneg, h2n, W1f, W2T,
                                               b_h1, nullptr, h1c, nullptr, kaA[i], kaB[i]);
        mm_fast<0, 0><<<gMM, 512, 0, stream>>>(h1c, nullptr, W2f, nullptr,
                                               b_h2, nullptr, h2n, nullptr, kbA[i], kbB[i]);
        mm_fast<2, 0><<<gMM, 512, 0, stream>>>(h1c, nullptr, W1T, nullptr,
                                               b_v, occ, vneg, nullptr, kcA[i], kcB[i]);
    }

    // final hidden refresh
    mm_fast<0, 1><<<gMM, 512, 0, stream>>>(vneg, h2n, W1f, W2T,
                                           b_h1, nullptr, h1c, nullptr, kfa, kfb);

    // outputs (weight scratch dead after this point)
    float* dW1o  = out + 1;
    float* dbvo  = dW1o + (size_t)NH * NV;
    float* dbh1o = dbvo + NV;
    float* dW2o  = dbh1o + NH;
    float* dbh2o = dW2o + (size_t)NH * NH;

    grad_mm<1><<<dim3(NSGN / 128, NH / 128), T, 0, stream>>>(h1c, vneg, h1d, (short*)nullptr, v_data, dW1o);
    grad_mm<0><<<dim3(NH / 128, NH / 128), T, 0, stream>>>(h1c, h2n, h1d, h2d, (const float*)nullptr, dW2o);
    dbv_fast<<<NSGN / 64, T, 0, stream>>>(v_data, vneg, dbvo);
    dbh_fast<<<NH / 64, T, 0, stream>>>(h1d, h1c, dbh1o);
    dbh_fast<<<NH / 64, T, 0, stream>>>(h2d, h2n, dbh2o);

    zero_kernel<<<1, 1, 0, stream>>>(cnt);
    loss_count2<<<1024, T, 0, stream>>>(v_data, vneg, cnt);
    loss_final_kernel<<<1, 1, 0, stream>>>(cnt, out, logf(1.0f + 1e-7f), logf(1e-7f));
}